// Round 9
// baseline (934.311 us; speedup 1.0000x reference)
//
#include <hip/hip_runtime.h>
#include <cstddef>
#include <cstdint>

#define NB 4
#define ND 512
#define NT 4096
#define NK 4096
#define NBT (NB * NT)
#define BKR 32         // real-k chunk
#define NCH (ND / BKR) // 16 chunks
#define CT (NK / 256)  // 16 candidate tiles

typedef __attribute__((ext_vector_type(4))) float f32x4;
typedef __attribute__((ext_vector_type(8))) short short8;
typedef __attribute__((ext_vector_type(8))) unsigned short u16x8;
typedef unsigned short u16;

__device__ inline u16 f2bf_rn(float f) {
  unsigned u = __float_as_uint(f);
  return (u16)((u + 0x7FFFu + ((u >> 16) & 1u)) >> 16);
}
__device__ inline float bf2f(u16 h) {
  return __uint_as_float(((unsigned)h) << 16);
}
__device__ inline void gload16(void* lds_p, const void* g) {
  __builtin_amdgcn_global_load_lds(
      (const __attribute__((address_space(1))) unsigned int*)g,
      (__attribute__((address_space(3))) unsigned int*)lds_p, 16, 0, 0);
}

// ---------------------------------------------------- e conversion + norm --
__global__ void conv_e_kernel(const float* __restrict__ emb,
                              u16* __restrict__ eh2, u16* __restrict__ el2,
                              float* __restrict__ enorm) {
  int row = blockIdx.x * 4 + (threadIdx.x >> 6);
  int l = threadIdx.x & 63;
  const float* e = emb + (size_t)row * ND;
  float s = 0.f;
#pragma unroll
  for (int i = 0; i < ND / 64; ++i) {
    int idx = l + i * 64;
    float v = e[idx];
    s += v * v;
    float v2 = 2.f * v;
    u16 h = f2bf_rn(v2);
    u16 lo = f2bf_rn(v2 - bf2f(h));
    eh2[(size_t)row * ND + idx] = h;
    el2[(size_t)row * ND + idx] = lo;
  }
#pragma unroll
  for (int m = 32; m; m >>= 1) s += __shfl_xor(s, m);
  if (l == 0) enorm[row] = s;
}

// ------------------- x conversion (+ transpose) + sum(x^2) partials --------
__global__ __launch_bounds__(256) void conv_x_kernel(const float* __restrict__ x,
                                                     u16* __restrict__ xh,
                                                     u16* __restrict__ xl,
                                                     float* __restrict__ xsq) {
  __shared__ float tile[64][68];
  const int tid = threadIdx.x;
  const int bt0 = blockIdx.x * 64, d0 = blockIdx.y * 64;
  const int b = bt0 / NT, t0 = bt0 % NT;
  const float* xb = x + (size_t)b * ND * NT;
  float s2 = 0.f;
  {
    const int tt4 = (tid & 15) * 4, ddb = tid >> 4;
#pragma unroll
    for (int p = 0; p < 4; ++p) {
      const int dd = ddb + p * 16;
      float4 v = *(const float4*)&xb[(size_t)(d0 + dd) * NT + t0 + tt4];
      s2 += v.x * v.x + v.y * v.y + v.z * v.z + v.w * v.w;
      *(float4*)&tile[dd][tt4] = v;
    }
  }
  __syncthreads();
  {
    const int t_loc = tid >> 2, dg = tid & 3;
    u16 hs[16], ls[16];
#pragma unroll
    for (int j = 0; j < 16; ++j) {
      float f = tile[dg * 16 + j][t_loc];
      u16 h = f2bf_rn(f);
      hs[j] = h;
      ls[j] = f2bf_rn(f - bf2f(h));
    }
    const size_t base = (size_t)(bt0 + t_loc) * ND + d0 + dg * 16;
    *(u16x8*)&xh[base] = *(const u16x8*)&hs[0];
    *(u16x8*)&xh[base + 8] = *(const u16x8*)&hs[8];
    *(u16x8*)&xl[base] = *(const u16x8*)&ls[0];
    *(u16x8*)&xl[base + 8] = *(const u16x8*)&ls[8];
  }
#pragma unroll
  for (int m = 32; m; m >>= 1) s2 += __shfl_xor(s2, m);
  __shared__ float wsum[4];
  if ((tid & 63) == 0) wsum[tid >> 6] = s2;
  __syncthreads();
  if (tid == 0)
    xsq[blockIdx.y * gridDim.x + blockIdx.x] =
        wsum[0] + wsum[1] + wsum[2] + wsum[3];
}

// ------------------------------------------------- 3-phase GEMM + argmin ---
// Quad-operand residency (r8) + REGISTER-PIPELINED fragment reads: each
// phase waits (lgkm) for fragments issued in the PREVIOUS phase, issues the
// next phase's ds_reads, then runs its MFMA burst -> the LDS-read pipe runs
// entirely under the MFMA bursts (MFMA is now the longer pipe).
// bH is register-double-buffered (bHa/bHb) via 2x-unrolled chunk loop; all
// other fragment arrays are dead by the time their next-read issues.
// Drain ledger (steady state): entry Q=[aL(c)2]; P0 issues stage aHbH(c+1),
// VMC(4) drains aL(c); P1 issues stage bL(c+1), VMC(2) drains aHbH(c+1)??
// -- no: drains the OLDEST 4-2=... see per-phase comments; every ds_read
// issue is covered by a prior counted-VMC+BAR on the data it samples.
__device__ __forceinline__ void stage_op(
    u16 (&lds)[2][4][256][BKR], int bn, int op, int tn,
    const u16* __restrict__ src, int rowbase, int w, int l) {
  if (tn >= NCH) return;
  const int kA = tn * BKR;
#pragma unroll
  for (int i = 0; i < 2; ++i) {
    const int rowL = i * 128 + w * 16 + (l >> 2);
    const int gslot = (l & 3) ^ ((rowL >> 1) & 3);
    gload16(&lds[bn][op][i * 128 + w * 16][0],
            &src[(size_t)(rowbase + rowL) * ND + kA + gslot * 8]);
  }
}

__global__ __launch_bounds__(512, 2) void argmin_gemm_kernel(
    const u16* __restrict__ xh, const u16* __restrict__ xl,
    const u16* __restrict__ eh2, const u16* __restrict__ el2,
    const float* __restrict__ enorm, float* __restrict__ cand_v,
    int* __restrict__ cand_i) {
  __shared__ u16 lds[2][4][256][BKR];  // [buf][aH,aL,bH,bL][row][k] = 128 KiB
  const int tid = threadIdx.x;
  const int w = tid >> 6, l = tid & 63;
  const int l15 = l & 15, l4 = l >> 4;
  const int wm = w >> 2, wn = w & 3;
  // XCD-aware bijective swizzle: nwg=1024, 128 blocks per XCD chunk.
  const int id = blockIdx.x;
  const int id_sw = (id & 7) * 128 + (id >> 3);
  const int bx = id_sw & 63, by = id_sw >> 6;
  const int bt0 = bx * 256, c0g = by * 256;

  f32x4 acc[2][4][2][2];  // [qm][m][qn][n]
#pragma unroll
  for (int qm = 0; qm < 2; ++qm)
#pragma unroll
    for (int m = 0; m < 4; ++m)
#pragma unroll
      for (int qn = 0; qn < 2; ++qn)
#pragma unroll
        for (int n = 0; n < 2; ++n) acc[qm][m][qn][n] = (f32x4)0.f;

  short8 aH[8], aL[8], bL[4], bHa[4], bHb[4];

#define SLOT(row) (((l4) ^ (((row) >> 1) & 3)) * 8)
#define DS_A_ISSUE(AF, OP, BUF)                                          \
  _Pragma("unroll") for (int qm = 0; qm < 2; ++qm) {                     \
    _Pragma("unroll") for (int m = 0; m < 4; ++m) {                      \
      const int row = wm * 128 + qm * 64 + m * 16 + l15;                 \
      AF[qm * 4 + m] = *(const short8*)&lds[BUF][OP][row][SLOT(row)];    \
    }                                                                    \
  }
#define DS_B_ISSUE(BF, OP, BUF)                                          \
  _Pragma("unroll") for (int qn = 0; qn < 2; ++qn) {                     \
    _Pragma("unroll") for (int n = 0; n < 2; ++n) {                      \
      const int row = wn * 64 + qn * 32 + n * 16 + l15;                  \
      BF[qn * 2 + n] = *(const short8*)&lds[BUF][OP][row][SLOT(row)];    \
    }                                                                    \
  }
#define MMP(AF, BF)                                                      \
  __builtin_amdgcn_s_setprio(1);                                         \
  _Pragma("unroll") for (int qm = 0; qm < 2; ++qm) {                     \
    _Pragma("unroll") for (int m = 0; m < 4; ++m) {                      \
      _Pragma("unroll") for (int qn = 0; qn < 2; ++qn) {                 \
        _Pragma("unroll") for (int n = 0; n < 2; ++n) {                  \
          acc[qm][m][qn][n] = __builtin_amdgcn_mfma_f32_16x16x32_bf16(   \
              AF[qm * 4 + m], BF[qn * 2 + n], acc[qm][m][qn][n], 0, 0,   \
              0);                                                        \
        }                                                                \
      }                                                                  \
    }                                                                    \
  }                                                                      \
  __builtin_amdgcn_s_setprio(0);
#define BAR __builtin_amdgcn_s_barrier()
#define SB0 __builtin_amdgcn_sched_barrier(0)
#define LGK                                              \
  asm volatile("s_waitcnt lgkmcnt(0)" ::: "memory");     \
  __builtin_amdgcn_sched_barrier(0)
#define VMC(N) asm volatile("s_waitcnt vmcnt(" #N ")" ::: "memory")

  // CHUNK(CUR,NBF,BHC,BHN,T): 3 phases, fragment reads pipelined 1 ahead.
  // P0: frags aH,BHC(T) ready; issue bL(T) reads [staged c-1, drained end
  //     P2(c-1)]; stage aHbH(T+1); MFMA aH*BHC; VMC(4) drains aL(T).
  // P1: bL ready; issue aL(T) reads [drained end P0(T)]; stage bL(T+1);
  //     MFMA aH*bL; VMC(2) drains aHbH(T+1) [for P2's read issue].
  // P2: aL ready; issue aH,BHN(T+1) reads from NBF; stage aL(T+1);
  //     MFMA aL*BHC; VMC(2) drains bL(T+1) [for next P0's read issue].
#define CHUNK(CUR, NBF, BHC, BHN, T)                                     \
  {                                                                      \
    const bool nlast = ((T) + 1 < NCH);                                  \
    LGK;                                                                 \
    DS_B_ISSUE(bL, 3, CUR);                                              \
    stage_op(lds, NBF, 0, (T) + 1, xh, bt0, w, l);                       \
    stage_op(lds, NBF, 2, (T) + 1, eh2, c0g, w, l);                      \
    SB0;                                                                 \
    MMP(aH, BHC);                                                        \
    if (nlast) { VMC(4); } else { VMC(0); }                              \
    BAR;                                                                 \
    LGK;                                                                 \
    DS_A_ISSUE(aL, 1, CUR);                                              \
    stage_op(lds, NBF, 3, (T) + 1, el2, c0g, w, l);                      \
    SB0;                                                                 \
    MMP(aH, bL);                                                         \
    if (nlast) { VMC(2); } else { VMC(0); }                              \
    BAR;                                                                 \
    LGK;                                                                 \
    if (nlast) {                                                         \
      DS_A_ISSUE(aH, 0, NBF);                                            \
      DS_B_ISSUE(BHN, 2, NBF);                                           \
    }                                                                    \
    stage_op(lds, NBF, 1, (T) + 1, xl, bt0, w, l);                       \
    SB0;                                                                 \
    MMP(aL, BHC);                                                        \
    if (nlast) { VMC(2); } else { VMC(0); }                              \
    BAR;                                                                 \
  }

  // prologue: stage chunk 0 (aH,bH,bL,aL); drain aHbH; issue their reads;
  // drain bL -> entry invariant Q=[aL(0)2], frag reads outstanding.
  stage_op(lds, 0, 0, 0, xh, bt0, w, l);   // aH(0)
  stage_op(lds, 0, 2, 0, eh2, c0g, w, l);  // bH(0)
  stage_op(lds, 0, 3, 0, el2, c0g, w, l);  // bL(0)
  stage_op(lds, 0, 1, 0, xl, bt0, w, l);   // aL(0)
  VMC(4);
  BAR;
  DS_A_ISSUE(aH, 0, 0);
  DS_B_ISSUE(bHa, 2, 0);
  VMC(2);
  BAR;

  for (int tt = 0; tt < NCH; tt += 2) {
    CHUNK(0, 1, bHa, bHb, tt);
    CHUNK(1, 0, bHb, bHa, tt + 1);
  }
#undef SLOT
#undef DS_A_ISSUE
#undef DS_B_ISSUE
#undef MMP
#undef CHUNK
#undef BAR
#undef SB0
#undef LGK
#undef VMC

  // ---- epilogue: per-row argmin over this block's 256 cols ----
  __syncthreads();  // all loads drained (vmcnt 0 at exit); LDS reused below
  float* cvs = (float*)&lds[0][0][0][0];  // [4][256]
  int* cis = (int*)(cvs + 4 * 256);       // [4][256]

  float bv[2][4][4];
  int bi[2][4][4];
#pragma unroll
  for (int qm = 0; qm < 2; ++qm)
#pragma unroll
    for (int m = 0; m < 4; ++m)
#pragma unroll
      for (int q = 0; q < 4; ++q) {
        bv[qm][m][q] = INFINITY;
        bi[qm][m][q] = 0;
      }
#pragma unroll
  for (int qn = 0; qn < 2; ++qn)  // ascending col order -> first-min ties
#pragma unroll
    for (int n = 0; n < 2; ++n) {
      const int col = c0g + wn * 64 + qn * 32 + n * 16 + l15;
      const float en = enorm[col];
#pragma unroll
      for (int qm = 0; qm < 2; ++qm)
#pragma unroll
        for (int m = 0; m < 4; ++m)
#pragma unroll
          for (int q = 0; q < 4; ++q) {
            const float s = en - acc[qm][m][qn][n][q];
            if (s < bv[qm][m][q]) {
              bv[qm][m][q] = s;
              bi[qm][m][q] = col;
            }
          }
    }
#pragma unroll
  for (int msk = 1; msk < 16; msk <<= 1) {
#pragma unroll
    for (int qm = 0; qm < 2; ++qm)
#pragma unroll
      for (int m = 0; m < 4; ++m)
#pragma unroll
        for (int q = 0; q < 4; ++q) {
          const float ov = __shfl_xor(bv[qm][m][q], msk);
          const int oi = __shfl_xor(bi[qm][m][q], msk);
          if (ov < bv[qm][m][q] || (ov == bv[qm][m][q] && oi < bi[qm][m][q])) {
            bv[qm][m][q] = ov;
            bi[qm][m][q] = oi;
          }
        }
  }
  if (l15 == 0) {
#pragma unroll
    for (int qm = 0; qm < 2; ++qm)
#pragma unroll
      for (int m = 0; m < 4; ++m)
#pragma unroll
        for (int q = 0; q < 4; ++q) {
          const int row = wm * 128 + qm * 64 + m * 16 + l4 * 4 + q;
          cvs[wn * 256 + row] = bv[qm][m][q];
          cis[wn * 256 + row] = bi[qm][m][q];
        }
  }
  __syncthreads();
  if (tid < 256) {
    float v = cvs[tid];
    int bidx = cis[tid];
#pragma unroll
    for (int q = 1; q < 4; ++q) {  // ascending wn -> ascending cols
      const float ov = cvs[q * 256 + tid];
      const int oi = cis[q * 256 + tid];
      if (ov < v) {
        v = ov;
        bidx = oi;
      }
    }
    cand_v[(size_t)by * NBT + bt0 + tid] = v;
    cand_i[(size_t)by * NBT + bt0 + tid] = bidx;
  }
}

// -------- combine + exact fp32 top-2 rescore + loss partial (s_best) -------
__global__ __launch_bounds__(256) void combine_rescore_kernel(
    const float* __restrict__ cand_v, const int* __restrict__ cand_i,
    const float* __restrict__ x, const float* __restrict__ emb,
    const float* __restrict__ enorm, int* __restrict__ idx_ws,
    float* __restrict__ idxf, float* __restrict__ lpart) {
  const int r = blockIdx.x * 256 + threadIdx.x;
  float v1 = INFINITY, v2 = INFINITY;
  int i1 = 0, i2 = 0;
#pragma unroll
  for (int nt = 0; nt < CT; ++nt) {  // ascending nt -> ascending index
    const float v = cand_v[(size_t)nt * NBT + r];
    const int i = cand_i[(size_t)nt * NBT + r];
    if (v < v1) {
      v2 = v1;
      i2 = i1;
      v1 = v;
      i1 = i;
    } else if (v < v2) {
      v2 = v;
      i2 = i;
    }
  }
  const int b = r >> 12, t = r & (NT - 1);
  const float* xb = x + (size_t)b * ND * NT + t;
  const float* e1 = emb + (size_t)i1 * ND;
  const float* e2 = emb + (size_t)i2 * ND;
  float d1 = 0.f, d2 = 0.f;
#pragma unroll 8
  for (int d = 0; d < ND; ++d) {
    const float xv = xb[(size_t)d * NT];
    d1 += xv * e1[d];
    d2 += xv * e2[d];
  }
  const float s1 = enorm[i1] - 2.f * d1;
  const float s2 = enorm[i2] - 2.f * d2;
  const bool take2 = (s2 < s1 || (s2 == s1 && i2 < i1));
  const int best = take2 ? i2 : i1;
  idx_ws[r] = best;
  idxf[r] = (float)best;
  // per-row loss term: sum_d (x-v)^2 - sum_d x^2 = enorm[best] - 2*dot_best
  float lsum = take2 ? s2 : s1;
#pragma unroll
  for (int m = 32; m; m >>= 1) lsum += __shfl_xor(lsum, m);
  __shared__ float wsum[4];
  if ((threadIdx.x & 63) == 0) wsum[threadIdx.x >> 6] = lsum;
  __syncthreads();
  if (threadIdx.x == 0)
    lpart[blockIdx.x] = wsum[0] + wsum[1] + wsum[2] + wsum[3];
}

// ----------------------------------------------- gather (emb -> [B,D,T]) ---
__global__ __launch_bounds__(256) void gather_kernel(
    const float* __restrict__ emb, const int* __restrict__ idx_ws,
    float* __restrict__ vals_out) {
  __shared__ float tile[64][65];
  const int tid = threadIdx.x;
  const int bt0 = blockIdx.x * 64;
  const int d0 = blockIdx.y * 64;
  const int b = bt0 / NT;
  const int t0 = bt0 % NT;
  {
    const int dd4 = (tid & 15) * 4;
    const int ttb = tid >> 4;
#pragma unroll
    for (int p = 0; p < 4; ++p) {
      const int tt = ttb + p * 16;
      const int r = idx_ws[bt0 + tt];
      float4 v = *(const float4*)&emb[(size_t)r * ND + d0 + dd4];
      tile[tt][dd4 + 0] = v.x;
      tile[tt][dd4 + 1] = v.y;
      tile[tt][dd4 + 2] = v.z;
      tile[tt][dd4 + 3] = v.w;
    }
  }
  __syncthreads();
  {
    const int tt4 = (tid & 15) * 4;
    const int ddb = tid >> 4;
#pragma unroll
    for (int p = 0; p < 4; ++p) {
      const int dd = ddb + p * 16;
      float4 v;
      v.x = tile[tt4 + 0][dd];
      v.y = tile[tt4 + 1][dd];
      v.z = tile[tt4 + 2][dd];
      v.w = tile[tt4 + 3][dd];
      const size_t o = (size_t)b * ND * NT + (size_t)(d0 + dd) * NT + t0 + tt4;
      *(float4*)&vals_out[o] = v;
    }
  }
}

// ----------------------------------------------------------------- loss ----
__global__ void loss_kernel(const float* __restrict__ partials, int n,
                            float* __restrict__ out) {
  float s = 0.f;
  for (int i = threadIdx.x; i < n; i += 256) s += partials[i];
#pragma unroll
  for (int m = 32; m; m >>= 1) s += __shfl_xor(s, m);
  __shared__ float wsum[4];
  if ((threadIdx.x & 63) == 0) wsum[threadIdx.x >> 6] = s;
  __syncthreads();
  if (threadIdx.x == 0)
    out[0] = 2.0f * (wsum[0] + wsum[1] + wsum[2] + wsum[3]) /
             (float)((size_t)NB * ND * NT);
}

// --------------------------------------------------------------- launch ----
extern "C" void kernel_launch(void* const* d_in, const int* in_sizes, int n_in,
                              void* d_out, int out_size, void* d_ws,
                              size_t ws_size, hipStream_t stream) {
  const float* x = (const float*)d_in[0];
  const float* emb = (const float*)d_in[1];
  float* out = (float*)d_out;
  float* vals_out = out;                         // [B, D, T]
  float* idxf_out = out + (size_t)NB * ND * NT;  // [B, T] as float
  float* loss_out = idxf_out + NBT;              // scalar

  u16* xh = (u16*)d_ws;                            // NBT*ND
  u16* xl = xh + (size_t)NBT * ND;                 // NBT*ND
  u16* eh2 = xl + (size_t)NBT * ND;                // NK*ND
  u16* el2 = eh2 + (size_t)NK * ND;                // NK*ND
  float* enorm = (float*)(el2 + (size_t)NK * ND);  // NK
  float* cand_v = enorm + NK;                      // CT * NBT
  int* cand_i = (int*)(cand_v + (size_t)CT * NBT);
  int* idx_ws = cand_i + (size_t)CT * NBT;  // NBT
  float* partials = (float*)(idx_ws + NBT); // 2048 (x^2) + 64 (rescore)

  conv_e_kernel<<<NK / 4, 256, 0, stream>>>(emb, eh2, el2, enorm);
  conv_x_kernel<<<dim3(NBT / 64, ND / 64), 256, 0, stream>>>(x, xh, xl,
                                                             partials);
  argmin_gemm_kernel<<<1024, 512, 0, stream>>>(xh, xl, eh2, el2, enorm, cand_v,
                                               cand_i);
  combine_rescore_kernel<<<NBT / 256, 256, 0, stream>>>(
      cand_v, cand_i, x, emb, enorm, idx_ws, idxf_out, partials + 2048);
  gather_kernel<<<dim3(NBT / 64, ND / 64), 256, 0, stream>>>(emb, idx_ws,
                                                             vals_out);
  loss_kernel<<<1, 256, 0, stream>>>(partials, 2048 + 64, loss_out);
}

// Round 10
// 275.641 us; speedup vs baseline: 3.3896x; 3.3896x over previous
//
#include <hip/hip_runtime.h>
#include <cstddef>
#include <cstdint>

#define NB 4
#define ND 512
#define NT 4096
#define NK 4096
#define NBT (NB * NT)
#define BKR 32         // real-k chunk
#define NCH (ND / BKR) // 16 chunks
#define CT (NK / 256)  // 16 candidate tiles

typedef __attribute__((ext_vector_type(4))) float f32x4;
typedef __attribute__((ext_vector_type(8))) short short8;
typedef __attribute__((ext_vector_type(8))) unsigned short u16x8;
typedef unsigned short u16;

__device__ inline u16 f2bf_rn(float f) {
  unsigned u = __float_as_uint(f);
  return (u16)((u + 0x7FFFu + ((u >> 16) & 1u)) >> 16);
}
__device__ inline float bf2f(u16 h) {
  return __uint_as_float(((unsigned)h) << 16);
}
__device__ inline void gload16(void* lds_p, const void* g) {
  __builtin_amdgcn_global_load_lds(
      (const __attribute__((address_space(1))) unsigned int*)g,
      (__attribute__((address_space(3))) unsigned int*)lds_p, 16, 0, 0);
}

// ---------------------------------------------------- e conversion + norm --
__global__ void conv_e_kernel(const float* __restrict__ emb,
                              u16* __restrict__ eh2, u16* __restrict__ el2,
                              float* __restrict__ enorm) {
  int row = blockIdx.x * 4 + (threadIdx.x >> 6);
  int l = threadIdx.x & 63;
  const float* e = emb + (size_t)row * ND;
  float s = 0.f;
#pragma unroll
  for (int i = 0; i < ND / 64; ++i) {
    int idx = l + i * 64;
    float v = e[idx];
    s += v * v;
    float v2 = 2.f * v;
    u16 h = f2bf_rn(v2);
    u16 lo = f2bf_rn(v2 - bf2f(h));
    eh2[(size_t)row * ND + idx] = h;
    el2[(size_t)row * ND + idx] = lo;
  }
#pragma unroll
  for (int m = 32; m; m >>= 1) s += __shfl_xor(s, m);
  if (l == 0) enorm[row] = s;
}

// ------------------- x conversion (+ transpose) + sum(x^2) partials --------
__global__ __launch_bounds__(256) void conv_x_kernel(const float* __restrict__ x,
                                                     u16* __restrict__ xh,
                                                     u16* __restrict__ xl,
                                                     float* __restrict__ xsq) {
  __shared__ float tile[64][68];
  const int tid = threadIdx.x;
  const int bt0 = blockIdx.x * 64, d0 = blockIdx.y * 64;
  const int b = bt0 / NT, t0 = bt0 % NT;
  const float* xb = x + (size_t)b * ND * NT;
  float s2 = 0.f;
  {
    const int tt4 = (tid & 15) * 4, ddb = tid >> 4;
#pragma unroll
    for (int p = 0; p < 4; ++p) {
      const int dd = ddb + p * 16;
      float4 v = *(const float4*)&xb[(size_t)(d0 + dd) * NT + t0 + tt4];
      s2 += v.x * v.x + v.y * v.y + v.z * v.z + v.w * v.w;
      *(float4*)&tile[dd][tt4] = v;
    }
  }
  __syncthreads();
  {
    const int t_loc = tid >> 2, dg = tid & 3;
    u16 hs[16], ls[16];
#pragma unroll
    for (int j = 0; j < 16; ++j) {
      float f = tile[dg * 16 + j][t_loc];
      u16 h = f2bf_rn(f);
      hs[j] = h;
      ls[j] = f2bf_rn(f - bf2f(h));
    }
    const size_t base = (size_t)(bt0 + t_loc) * ND + d0 + dg * 16;
    *(u16x8*)&xh[base] = *(const u16x8*)&hs[0];
    *(u16x8*)&xh[base + 8] = *(const u16x8*)&hs[8];
    *(u16x8*)&xl[base] = *(const u16x8*)&ls[0];
    *(u16x8*)&xl[base + 8] = *(const u16x8*)&ls[8];
  }
#pragma unroll
  for (int m = 32; m; m >>= 1) s2 += __shfl_xor(s2, m);
  __shared__ float wsum[4];
  if ((tid & 63) == 0) wsum[tid >> 6] = s2;
  __syncthreads();
  if (tid == 0)
    xsq[blockIdx.y * gridDim.x + blockIdx.x] =
        wsum[0] + wsum[1] + wsum[2] + wsum[3];
}

// ------------------------------------------------- 3-phase GEMM + argmin ---
// r8 quad-operand residency + COMPILER-SCHEDULED ds_read/MFMA interleave:
// no forced lgkmcnt(0) drain before the MFMA burst — the ds_reads are plain
// C++ LDS loads, so hipcc emits fine-grained lgkmcnt(N) waits interleaved
// into the burst (first MFMAs start as soon as their fragments land, the
// remaining reads complete under the burst). Cross-wave safety: each phase's
// reads are covered by the previous phase's counted VMC (asm memory clobber
// blocks hoisting above it) + BAR, and sched_barrier(0) directly after each
// BAR pins reads below the barrier. VMC ledger identical to r8 (verified).
__device__ __forceinline__ void stage_op(
    u16 (&lds)[2][4][256][BKR], int bn, int op, int tn,
    const u16* __restrict__ src, int rowbase, int w, int l) {
  if (tn >= NCH) return;
  const int kA = tn * BKR;
#pragma unroll
  for (int i = 0; i < 2; ++i) {
    const int rowL = i * 128 + w * 16 + (l >> 2);
    const int gslot = (l & 3) ^ ((rowL >> 1) & 3);
    gload16(&lds[bn][op][i * 128 + w * 16][0],
            &src[(size_t)(rowbase + rowL) * ND + kA + gslot * 8]);
  }
}

__global__ __launch_bounds__(512, 2) void argmin_gemm_kernel(
    const u16* __restrict__ xh, const u16* __restrict__ xl,
    const u16* __restrict__ eh2, const u16* __restrict__ el2,
    const float* __restrict__ enorm, float* __restrict__ cand_v,
    int* __restrict__ cand_i) {
  __shared__ u16 lds[2][4][256][BKR];  // [buf][aH,aL,bH,bL][row][k] = 128 KiB
  const int tid = threadIdx.x;
  const int w = tid >> 6, l = tid & 63;
  const int l15 = l & 15, l4 = l >> 4;
  const int wm = w >> 2, wn = w & 3;
  // XCD-aware bijective swizzle: nwg=1024, 128 blocks per XCD chunk.
  const int id = blockIdx.x;
  const int id_sw = (id & 7) * 128 + (id >> 3);
  const int bx = id_sw & 63, by = id_sw >> 6;
  const int bt0 = bx * 256, c0g = by * 256;

  f32x4 acc[2][4][2][2];  // [qm][m][qn][n]
#pragma unroll
  for (int qm = 0; qm < 2; ++qm)
#pragma unroll
    for (int m = 0; m < 4; ++m)
#pragma unroll
      for (int qn = 0; qn < 2; ++qn)
#pragma unroll
        for (int n = 0; n < 2; ++n) acc[qm][m][qn][n] = (f32x4)0.f;

  short8 aH[8], aL[8], bH[4], bL[4];

#define SLOT(row) (((l4) ^ (((row) >> 1) & 3)) * 8)
#define DS_A(AF, OP)                                                     \
  _Pragma("unroll") for (int qm = 0; qm < 2; ++qm) {                     \
    _Pragma("unroll") for (int m = 0; m < 4; ++m) {                      \
      const int row = wm * 128 + qm * 64 + m * 16 + l15;                 \
      AF[qm * 4 + m] = *(const short8*)&lds[cur][OP][row][SLOT(row)];    \
    }                                                                    \
  }
#define DS_B(BF, OP)                                                     \
  _Pragma("unroll") for (int qn = 0; qn < 2; ++qn) {                     \
    _Pragma("unroll") for (int n = 0; n < 2; ++n) {                      \
      const int row = wn * 64 + qn * 32 + n * 16 + l15;                  \
      BF[qn * 2 + n] = *(const short8*)&lds[cur][OP][row][SLOT(row)];    \
    }                                                                    \
  }
#define MMP(AF, BF)                                                      \
  __builtin_amdgcn_s_setprio(1);                                         \
  _Pragma("unroll") for (int qm = 0; qm < 2; ++qm) {                     \
    _Pragma("unroll") for (int m = 0; m < 4; ++m) {                      \
      _Pragma("unroll") for (int qn = 0; qn < 2; ++qn) {                 \
        _Pragma("unroll") for (int n = 0; n < 2; ++n) {                  \
          acc[qm][m][qn][n] = __builtin_amdgcn_mfma_f32_16x16x32_bf16(   \
              AF[qm * 4 + m], BF[qn * 2 + n], acc[qm][m][qn][n], 0, 0,   \
              0);                                                        \
        }                                                                \
      }                                                                  \
    }                                                                    \
  }                                                                      \
  __builtin_amdgcn_s_setprio(0);
#define BAR __builtin_amdgcn_s_barrier()
#define SB0 __builtin_amdgcn_sched_barrier(0)
#define VMC(N) asm volatile("s_waitcnt vmcnt(" #N ")" ::: "memory")

  // prologue: stage chunk 0 (order aH,bH,bL,aL; 8 loads/thread);
  // VMC(4) drains aH,bH -> loop invariant Q=[bL(c)2, aL(c)2].
  stage_op(lds, 0, 0, 0, xh, bt0, w, l);   // aH
  stage_op(lds, 0, 2, 0, eh2, c0g, w, l);  // bH
  stage_op(lds, 0, 3, 0, el2, c0g, w, l);  // bL
  stage_op(lds, 0, 1, 0, xl, bt0, w, l);   // aL
  VMC(4);
  BAR;
  SB0;

  for (int t = 0; t < NCH; ++t) {
    const int cur = t & 1;
    const int nb = cur ^ 1;
    const int tn = t + 1;
    const bool last = (t == NCH - 1);
    // ---- P0: stage aH,bH(c+1); read aH,bH(c); MFMA aH*bH ----
    stage_op(lds, nb, 0, tn, xh, bt0, w, l);
    stage_op(lds, nb, 2, tn, eh2, c0g, w, l);
    DS_A(aH, 0);
    DS_B(bH, 2);
    MMP(aH, bH);
    if (last) {       // Q=[bL,aL]: drain bL
      VMC(2);
    } else {          // Q=[bL(c)2,aL(c)2,aHbH(c+1)4]=8: drain bL(c)
      VMC(6);
    }
    BAR;
    SB0;
    // ---- P1: stage bL(c+1); read bL(c); MFMA aH*bL ----
    stage_op(lds, nb, 3, tn, el2, c0g, w, l);
    DS_B(bL, 3);
    MMP(aH, bL);
    if (last) {
      VMC(0);
    } else {          // Q=[aL(c)2,aHbH(c+1)4,bL(c+1)2]=8: drain aL(c)
      VMC(6);
    }
    BAR;
    SB0;
    // ---- P2: stage aL(c+1); read aL(c); MFMA aL*bH ----
    stage_op(lds, nb, 1, tn, xl, bt0, w, l);
    DS_A(aL, 1);
    MMP(aL, bH);
    if (last) {
      VMC(0);
    } else {          // Q=[aHbH(c+1)4,bL(c+1)2,aL(c+1)2]=8: drain aH,bH
      VMC(4);
    }
    BAR;
    SB0;
  }
#undef SLOT
#undef DS_A
#undef DS_B
#undef MMP
#undef BAR
#undef SB0
#undef VMC

  // ---- epilogue: per-row argmin over this block's 256 cols ----
  __syncthreads();  // all loads drained (vmcnt 0 at exit); LDS reused below
  float* cvs = (float*)&lds[0][0][0][0];  // [4][256]
  int* cis = (int*)(cvs + 4 * 256);       // [4][256]

  float bv[2][4][4];
  int bi[2][4][4];
#pragma unroll
  for (int qm = 0; qm < 2; ++qm)
#pragma unroll
    for (int m = 0; m < 4; ++m)
#pragma unroll
      for (int q = 0; q < 4; ++q) {
        bv[qm][m][q] = INFINITY;
        bi[qm][m][q] = 0;
      }
#pragma unroll
  for (int qn = 0; qn < 2; ++qn)  // ascending col order -> first-min ties
#pragma unroll
    for (int n = 0; n < 2; ++n) {
      const int col = c0g + wn * 64 + qn * 32 + n * 16 + l15;
      const float en = enorm[col];
#pragma unroll
      for (int qm = 0; qm < 2; ++qm)
#pragma unroll
        for (int m = 0; m < 4; ++m)
#pragma unroll
          for (int q = 0; q < 4; ++q) {
            const float s = en - acc[qm][m][qn][n][q];
            if (s < bv[qm][m][q]) {
              bv[qm][m][q] = s;
              bi[qm][m][q] = col;
            }
          }
    }
#pragma unroll
  for (int msk = 1; msk < 16; msk <<= 1) {
#pragma unroll
    for (int qm = 0; qm < 2; ++qm)
#pragma unroll
      for (int m = 0; m < 4; ++m)
#pragma unroll
        for (int q = 0; q < 4; ++q) {
          const float ov = __shfl_xor(bv[qm][m][q], msk);
          const int oi = __shfl_xor(bi[qm][m][q], msk);
          if (ov < bv[qm][m][q] || (ov == bv[qm][m][q] && oi < bi[qm][m][q])) {
            bv[qm][m][q] = ov;
            bi[qm][m][q] = oi;
          }
        }
  }
  if (l15 == 0) {
#pragma unroll
    for (int qm = 0; qm < 2; ++qm)
#pragma unroll
      for (int m = 0; m < 4; ++m)
#pragma unroll
        for (int q = 0; q < 4; ++q) {
          const int row = wm * 128 + qm * 64 + m * 16 + l4 * 4 + q;
          cvs[wn * 256 + row] = bv[qm][m][q];
          cis[wn * 256 + row] = bi[qm][m][q];
        }
  }
  __syncthreads();
  if (tid < 256) {
    float v = cvs[tid];
    int bidx = cis[tid];
#pragma unroll
    for (int q = 1; q < 4; ++q) {  // ascending wn -> ascending cols
      const float ov = cvs[q * 256 + tid];
      const int oi = cis[q * 256 + tid];
      if (ov < v) {
        v = ov;
        bidx = oi;
      }
    }
    cand_v[(size_t)by * NBT + bt0 + tid] = v;
    cand_i[(size_t)by * NBT + bt0 + tid] = bidx;
  }
}

// -------- combine + exact fp32 top-2 rescore + loss partial (s_best) -------
__global__ __launch_bounds__(256) void combine_rescore_kernel(
    const float* __restrict__ cand_v, const int* __restrict__ cand_i,
    const float* __restrict__ x, const float* __restrict__ emb,
    const float* __restrict__ enorm, int* __restrict__ idx_ws,
    float* __restrict__ idxf, float* __restrict__ lpart) {
  const int r = blockIdx.x * 256 + threadIdx.x;
  float v1 = INFINITY, v2 = INFINITY;
  int i1 = 0, i2 = 0;
#pragma unroll
  for (int nt = 0; nt < CT; ++nt) {  // ascending nt -> ascending index
    const float v = cand_v[(size_t)nt * NBT + r];
    const int i = cand_i[(size_t)nt * NBT + r];
    if (v < v1) {
      v2 = v1;
      i2 = i1;
      v1 = v;
      i1 = i;
    } else if (v < v2) {
      v2 = v;
      i2 = i;
    }
  }
  const int b = r >> 12, t = r & (NT - 1);
  const float* xb = x + (size_t)b * ND * NT + t;
  const float* e1 = emb + (size_t)i1 * ND;
  const float* e2 = emb + (size_t)i2 * ND;
  float d1 = 0.f, d2 = 0.f;
#pragma unroll 8
  for (int d = 0; d < ND; ++d) {
    const float xv = xb[(size_t)d * NT];
    d1 += xv * e1[d];
    d2 += xv * e2[d];
  }
  const float s1 = enorm[i1] - 2.f * d1;
  const float s2 = enorm[i2] - 2.f * d2;
  const bool take2 = (s2 < s1 || (s2 == s1 && i2 < i1));
  const int best = take2 ? i2 : i1;
  idx_ws[r] = best;
  idxf[r] = (float)best;
  // per-row loss term: sum_d (x-v)^2 - sum_d x^2 = enorm[best] - 2*dot_best
  float lsum = take2 ? s2 : s1;
#pragma unroll
  for (int m = 32; m; m >>= 1) lsum += __shfl_xor(lsum, m);
  __shared__ float wsum[4];
  if ((threadIdx.x & 63) == 0) wsum[threadIdx.x >> 6] = lsum;
  __syncthreads();
  if (threadIdx.x == 0)
    lpart[blockIdx.x] = wsum[0] + wsum[1] + wsum[2] + wsum[3];
}

// ----------------------------------------------- gather (emb -> [B,D,T]) ---
__global__ __launch_bounds__(256) void gather_kernel(
    const float* __restrict__ emb, const int* __restrict__ idx_ws,
    float* __restrict__ vals_out) {
  __shared__ float tile[64][65];
  const int tid = threadIdx.x;
  const int bt0 = blockIdx.x * 64;
  const int d0 = blockIdx.y * 64;
  const int b = bt0 / NT;
  const int t0 = bt0 % NT;
  {
    const int dd4 = (tid & 15) * 4;
    const int ttb = tid >> 4;
#pragma unroll
    for (int p = 0; p < 4; ++p) {
      const int tt = ttb + p * 16;
      const int r = idx_ws[bt0 + tt];
      float4 v = *(const float4*)&emb[(size_t)r * ND + d0 + dd4];
      tile[tt][dd4 + 0] = v.x;
      tile[tt][dd4 + 1] = v.y;
      tile[tt][dd4 + 2] = v.z;
      tile[tt][dd4 + 3] = v.w;
    }
  }
  __syncthreads();
  {
    const int tt4 = (tid & 15) * 4;
    const int ddb = tid >> 4;
#pragma unroll
    for (int p = 0; p < 4; ++p) {
      const int dd = ddb + p * 16;
      float4 v;
      v.x = tile[tt4 + 0][dd];
      v.y = tile[tt4 + 1][dd];
      v.z = tile[tt4 + 2][dd];
      v.w = tile[tt4 + 3][dd];
      const size_t o = (size_t)b * ND * NT + (size_t)(d0 + dd) * NT + t0 + tt4;
      *(float4*)&vals_out[o] = v;
    }
  }
}

// ----------------------------------------------------------------- loss ----
__global__ void loss_kernel(const float* __restrict__ partials, int n,
                            float* __restrict__ out) {
  float s = 0.f;
  for (int i = threadIdx.x; i < n; i += 256) s += partials[i];
#pragma unroll
  for (int m = 32; m; m >>= 1) s += __shfl_xor(s, m);
  __shared__ float wsum[4];
  if ((threadIdx.x & 63) == 0) wsum[threadIdx.x >> 6] = s;
  __syncthreads();
  if (threadIdx.x == 0)
    out[0] = 2.0f * (wsum[0] + wsum[1] + wsum[2] + wsum[3]) /
             (float)((size_t)NB * ND * NT);
}

// --------------------------------------------------------------- launch ----
extern "C" void kernel_launch(void* const* d_in, const int* in_sizes, int n_in,
                              void* d_out, int out_size, void* d_ws,
                              size_t ws_size, hipStream_t stream) {
  const float* x = (const float*)d_in[0];
  const float* emb = (const float*)d_in[1];
  float* out = (float*)d_out;
  float* vals_out = out;                         // [B, D, T]
  float* idxf_out = out + (size_t)NB * ND * NT;  // [B, T] as float
  float* loss_out = idxf_out + NBT;              // scalar

  u16* xh = (u16*)d_ws;                            // NBT*ND
  u16* xl = xh + (size_t)NBT * ND;                 // NBT*ND
  u16* eh2 = xl + (size_t)NBT * ND;                // NK*ND
  u16* el2 = eh2 + (size_t)NK * ND;                // NK*ND
  float* enorm = (float*)(el2 + (size_t)NK * ND);  // NK
  float* cand_v = enorm + NK;                      // CT * NBT
  int* cand_i = (int*)(cand_v + (size_t)CT * NBT);
  int* idx_ws = cand_i + (size_t)CT * NBT;  // NBT
  float* partials = (float*)(idx_ws + NBT); // 2048 (x^2) + 64 (rescore)

  conv_e_kernel<<<NK / 4, 256, 0, stream>>>(emb, eh2, el2, enorm);
  conv_x_kernel<<<dim3(NBT / 64, ND / 64), 256, 0, stream>>>(x, xh, xl,
                                                             partials);
  argmin_gemm_kernel<<<1024, 512, 0, stream>>>(xh, xl, eh2, el2, enorm, cand_v,
                                               cand_i);
  combine_rescore_kernel<<<NBT / 256, 256, 0, stream>>>(
      cand_v, cand_i, x, emb, enorm, idx_ws, idxf_out, partials + 2048);
  gather_kernel<<<dim3(NBT / 64, ND / 64), 256, 0, stream>>>(emb, idx_ws,
                                                             vals_out);
  loss_kernel<<<1, 256, 0, stream>>>(partials, 2048 + 64, loss_out);
}